// Round 11
// baseline (479.786 us; speedup 1.0000x reference)
//
#include <hip/hip_runtime.h>

typedef unsigned short u16;
typedef unsigned int u32;
typedef __attribute__((ext_vector_type(8))) short short8v;   // 8 bf16 (4 VGPRs)
typedef __attribute__((ext_vector_type(4))) float f32x4;

#define V_N 100000
#define C_N 50000
#define E_N 1250000
#define VF_N 32
#define H_N 64
#define ROUNDS 3

#define TILE 4096
#define NT ((E_N + TILE - 1) / TILE)      // 306 edge tiles
#define NB_C ((C_N + 127) / 128)          // 391 coarse buckets (128 dests each)
#define NB_V ((V_N + 255) / 256)          // 391 coarse buckets (256 dests each)
#define FC_BLOCKS 768                     // 3 blocks/CU (50KB LDS each) persistent
#define KPAD 72                           // plane row stride in u16 elements
#define NTILES_C ((C_N + 15) / 16)        // 3125 dest tiles

static __device__ __forceinline__ float bf2f(u16 x) {
  return __uint_as_float(((u32)x) << 16);
}
static __device__ __forceinline__ u16 f2bf(float f) {
  u32 u = __float_as_uint(f);
  u32 r = (u + 0x7fff + ((u >> 16) & 1)) >> 16;  // RNE
  return (u16)r;
}

// ---------------- CSR build: two-level bucket sort, block-aggregated atomics ----

__global__ __launch_bounds__(256) void bucket_hist(const int* __restrict__ vi,
                                                   const int* __restrict__ ci,
                                                   int* __restrict__ gh_c,
                                                   int* __restrict__ gh_v) {
  __shared__ int hc[NB_C], hv[NB_V];
  int t = threadIdx.x;
  for (int j = t; j < NB_C; j += 256) hc[j] = 0;
  for (int j = t; j < NB_V; j += 256) hv[j] = 0;
  __syncthreads();
  int base = blockIdx.x * TILE;
#pragma unroll
  for (int i = 0; i < 16; ++i) {
    int idx = base + i * 256 + t;
    if (idx < E_N) {
      atomicAdd(&hc[ci[idx] >> 7], 1);
      atomicAdd(&hv[vi[idx] >> 8], 1);
    }
  }
  __syncthreads();
  for (int j = t; j < NB_C; j += 256) if (hc[j]) atomicAdd(&gh_c[j], hc[j]);
  for (int j = t; j < NB_V; j += 256) if (hv[j]) atomicAdd(&gh_v[j], hv[j]);
}

__global__ __launch_bounds__(512) void bucket_scan(const int* __restrict__ gh_c,
                                                   const int* __restrict__ gh_v,
                                                   int* __restrict__ base_c,
                                                   int* __restrict__ cursor_c,
                                                   int* __restrict__ base_v,
                                                   int* __restrict__ cursor_v,
                                                   int* __restrict__ rs_c,
                                                   int* __restrict__ rs_v) {
  __shared__ int lds[512];
  int t = threadIdx.x;
  int x = (t < NB_C) ? gh_c[t] : 0;
  lds[t] = x;
  __syncthreads();
  for (int off = 1; off < 512; off <<= 1) {
    int v = (t >= off) ? lds[t - off] : 0;
    __syncthreads();
    lds[t] += v;
    __syncthreads();
  }
  int excl = lds[t] - x;
  if (t < NB_C) { base_c[t] = excl; cursor_c[t] = excl; }
  if (t == 511) base_c[NB_C] = lds[511];
  __syncthreads();
  int y = (t < NB_V) ? gh_v[t] : 0;
  lds[t] = y;
  __syncthreads();
  for (int off = 1; off < 512; off <<= 1) {
    int v = (t >= off) ? lds[t - off] : 0;
    __syncthreads();
    lds[t] += v;
    __syncthreads();
  }
  int excl2 = lds[t] - y;
  if (t < NB_V) { base_v[t] = excl2; cursor_v[t] = excl2; }
  if (t == 511) base_v[NB_V] = lds[511];
  if (t == 0) { rs_c[C_N] = E_N; rs_v[V_N] = E_N; }
}

// Packed element: (local_dest << 17) | src_id   (src < 2^17, local_dest <= 255)
__global__ __launch_bounds__(256) void scatter_pack(const int* __restrict__ vi,
                                                    const int* __restrict__ ci,
                                                    int* __restrict__ cursor_c,
                                                    int* __restrict__ cursor_v,
                                                    int* __restrict__ packed_c,
                                                    int* __restrict__ packed_v) {
  __shared__ int hc[NB_C], hv[NB_V], sc[NB_C], sv[NB_V];
  int t = threadIdx.x;
  for (int j = t; j < NB_C; j += 256) hc[j] = 0;
  for (int j = t; j < NB_V; j += 256) hv[j] = 0;
  __syncthreads();
  int base = blockIdx.x * TILE;
  int cc[16], vv[16];
#pragma unroll
  for (int i = 0; i < 16; ++i) {
    int idx = base + i * 256 + t;
    if (idx < E_N) {
      cc[i] = ci[idx];
      vv[i] = vi[idx];
      atomicAdd(&hc[cc[i] >> 7], 1);
      atomicAdd(&hv[vv[i] >> 8], 1);
    } else {
      cc[i] = -1;
      vv[i] = -1;
    }
  }
  __syncthreads();
  for (int j = t; j < NB_C; j += 256) {
    int n = hc[j];
    if (n > 0) sc[j] = atomicAdd(&cursor_c[j], n);
    hc[j] = 0;
  }
  for (int j = t; j < NB_V; j += 256) {
    int n = hv[j];
    if (n > 0) sv[j] = atomicAdd(&cursor_v[j], n);
    hv[j] = 0;
  }
  __syncthreads();
#pragma unroll
  for (int i = 0; i < 16; ++i) {
    if (cc[i] >= 0) {
      int b = cc[i] >> 7;
      int r = atomicAdd(&hc[b], 1);
      packed_c[sc[b] + r] = ((cc[i] & 127) << 17) | vv[i];
      int b2 = vv[i] >> 8;
      int r2 = atomicAdd(&hv[b2], 1);
      packed_v[sv[b2] + r2] = ((vv[i] & 255) << 17) | cc[i];
    }
  }
}

template <int LOCAL_N, int N_DEST>
__global__ __launch_bounds__(256) void fine_sort(const int* __restrict__ packed,
                                                 const int* __restrict__ base,
                                                 int* __restrict__ rs,
                                                 int* __restrict__ srco) {
  __shared__ int cnt[LOCAL_N];
  __shared__ int excl[LOCAL_N];
  int b = blockIdx.x, t = threadIdx.x;
  int s0 = base[b], s1 = base[b + 1];
  if (t < LOCAL_N) cnt[t] = 0;
  __syncthreads();
  for (int i = s0 + t; i < s1; i += 256) atomicAdd(&cnt[packed[i] >> 17], 1);
  __syncthreads();
  if (t == 0) {
    int run = 0;
    for (int k = 0; k < LOCAL_N; ++k) { excl[k] = run; run += cnt[k]; }
  }
  __syncthreads();
  if (t < LOCAL_N) {
    int d = b * LOCAL_N + t;
    if (d < N_DEST) rs[d] = s0 + excl[t];
    cnt[t] = excl[t];
  }
  __syncthreads();
  for (int i = s0 + t; i < s1; i += 256) {
    int w = packed[i];
    int ld = w >> 17;
    int pos = s0 + atomicAdd(&cnt[ld], 1);
    srco[pos] = w & 0x1FFFF;
  }
}

// ---------------- W prep: split W1,W2 into bf16 hi/lo planes, transposed [col][k]

__global__ __launch_bounds__(256) void prep_w(const float* __restrict__ W1,
                                              const float* __restrict__ W2,
                                              u16* __restrict__ wp) {
  int i = blockIdx.x * 256 + threadIdx.x;
  if (i >= H_N * H_N) return;
  int k = i >> 6, n = i & 63;
  float w1 = W1[i];
  u16 h1 = f2bf(w1);
  u16 l1 = f2bf(w1 - bf2f(h1));
  wp[(0 * 64 + n) * 64 + k] = h1;       // mat0 hi
  wp[(1 * 64 + n) * 64 + k] = l1;       // mat0 lo
  float w2 = W2[i];
  u16 h2 = f2bf(w2);
  u16 l2 = f2bf(w2 - bf2f(h2));
  wp[(2 * 64 + n) * 64 + k] = h2;       // mat1 hi
  wp[(3 * 64 + n) * 64 + k] = l2;       // mat1 lo
}

// ---------------- input MLP: h = relu(feat[n,32] @ W[32,64] + b) ----------------

template <int WRITE_BF>
__global__ __launch_bounds__(256) void init_mlp(const float* __restrict__ feat,
                                                const float* __restrict__ W,
                                                const float* __restrict__ b,
                                                float* __restrict__ h,
                                                u16* __restrict__ hbf, int n) {
  __shared__ float Wl[VF_N * H_N];
  for (int i = threadIdx.x; i < VF_N * H_N; i += 256) Wl[i] = W[i];
  __syncthreads();
  int g = (blockIdx.x * 256 + threadIdx.x) >> 4;
  int lane = threadIdx.x & 15;
  if (g >= n) return;
  float2 rv = *(const float2*)&feat[(size_t)g * VF_N + lane * 2];
  float4 acc = *(const float4*)&b[lane * 4];
#pragma unroll
  for (int k = 0; k < VF_N; ++k) {
    float el = (k & 1) ? rv.y : rv.x;
    float v = __shfl(el, k >> 1, 16);
    float4 w = *(const float4*)&Wl[k * H_N + lane * 4];
    acc.x += v * w.x; acc.y += v * w.y; acc.z += v * w.z; acc.w += v * w.w;
  }
  acc.x = fmaxf(acc.x, 0.f); acc.y = fmaxf(acc.y, 0.f);
  acc.z = fmaxf(acc.z, 0.f); acc.w = fmaxf(acc.w, 0.f);
  *(float4*)&h[(size_t)g * H_N + lane * 4] = acc;
  if (WRITE_BF) {
    ushort4 q;
    q.x = f2bf(acc.x); q.y = f2bf(acc.y); q.z = f2bf(acc.z); q.w = f2bf(acc.w);
    *(ushort4*)&hbf[(size_t)g * H_N + lane * 4] = q;
  }
}

// ---------------- batched bf16 row gather (8B/lane, 16 deep, 32-VGPR buffer) ---

static __device__ __forceinline__ void gather_rows_bf16(const u16* __restrict__ tbl,
                                                        const int* __restrict__ src,
                                                        int s, int e, int lane,
                                                        float4& acc) {
  int p = s;
  for (; p + 16 <= e; p += 16) {
    int myidx = src[p + lane];
    ushort4 vv[16];
#pragma unroll
    for (int j = 0; j < 16; ++j) {
      int sj = __shfl(myidx, j, 16);
      vv[j] = *(const ushort4*)&tbl[(size_t)sj * H_N + lane * 4];
    }
#pragma unroll
    for (int j = 0; j < 16; ++j) {
      acc.x += bf2f(vv[j].x); acc.y += bf2f(vv[j].y);
      acc.z += bf2f(vv[j].z); acc.w += bf2f(vv[j].w);
    }
  }
  if (p < e) {
    int cnt = e - p;
    int myidx = (lane < cnt) ? src[p + lane] : 0;
    ushort4 vv[16];
#pragma unroll
    for (int j = 0; j < 16; ++j) {
      int sj = __shfl(myidx, j, 16);
      vv[j] = *(const ushort4*)&tbl[(size_t)sj * H_N + lane * 4];
    }
#pragma unroll
    for (int j = 0; j < 16; ++j) {
      if (j < cnt) {
        acc.x += bf2f(vv[j].x); acc.y += bf2f(vv[j].y);
        acc.z += bf2f(vv[j].z); acc.w += bf2f(vv[j].w);
      }
    }
  }
}

// ---------------- fused C-side update (persistent, MFMA, dynamic queue) --------
//   s      = segsum_c(h_var_bf)                (bf16 gather, fp32 accumulate)
//   h_con  = relu(h_con + s @ W1 + b1)         (MFMA, hi/lo compensated)
//   t_bf   = bf16(h_con @ W2)                  (MFMA, hi/lo compensated)
// Round-10 lesson: the 16x16B wide gather needed 64 VGPRs of load buffer,
// which halved memory-level parallelism (VGPR 68->84, VALUBusy 20->10%,
// 2x slower). Reverted to the 8B/lane 16-deep gather; kept the dynamic
// tile queue (fixes round-9's static-assignment tail, occ 16.7->24%).

__global__ __launch_bounds__(256) void fused_c(const u16* __restrict__ h_var_bf,
                                               const int* __restrict__ rs,
                                               const int* __restrict__ src,
                                               const u16* __restrict__ wp,
                                               const float* __restrict__ b1g,
                                               float* __restrict__ h_con,
                                               u16* __restrict__ t_out,
                                               int* __restrict__ tile_ctr) {
  __shared__ u16 Wlds[4 * 64 * 64];            // 32768 B: [mat*2+pl][col][k]
  __shared__ u16 Aplanes[4][2 * 16 * KPAD];    // 4 waves x 4608 B: [pl][row][KPAD]

  for (int i = threadIdx.x; i < 4 * 64 * 64 / 2; i += 256)
    ((u32*)Wlds)[i] = ((const u32*)wp)[i];
  __syncthreads();

  int lane64 = threadIdx.x & 63;
  int wave = threadIdx.x >> 6;
  int lane = threadIdx.x & 15;
  int grp = (threadIdx.x >> 4) & 3;
  int arow = lane64 & 15;     // A row / D col (within tile)
  int kq = lane64 >> 4;       // k-octet selector / D row-quad
  u16* P = &Aplanes[wave][0];

  float bias[4];
#pragma unroll
  for (int nt = 0; nt < 4; ++nt) bias[nt] = b1g[nt * 16 + arow];

  for (;;) {
    int tile = 0;
    if (lane64 == 0) tile = atomicAdd(tile_ctr, 1);
    tile = __shfl(tile, 0, 64);
    if (tile >= NTILES_C) break;
    int base = tile * 16;
    // ---- gather: group handles rows {grp, 4+grp, 8+grp, 12+grp}; stage hi/lo
    for (int q = 0; q < 4; ++q) {
      int row = 4 * q + grp;
      int g = base + row;
      float4 acc = {0.f, 0.f, 0.f, 0.f};
      if (g < C_N) gather_rows_bf16(h_var_bf, src, rs[g], rs[g + 1], lane, acc);
      ushort4 qh, ql;
      qh.x = f2bf(acc.x); ql.x = f2bf(acc.x - bf2f(qh.x));
      qh.y = f2bf(acc.y); ql.y = f2bf(acc.y - bf2f(qh.y));
      qh.z = f2bf(acc.z); ql.z = f2bf(acc.z - bf2f(qh.z));
      qh.w = f2bf(acc.w); ql.w = f2bf(acc.w - bf2f(qh.w));
      *(ushort4*)&P[0 * 16 * KPAD + row * KPAD + lane * 4] = qh;
      *(ushort4*)&P[1 * 16 * KPAD + row * KPAD + lane * 4] = ql;
    }
    asm volatile("" ::: "memory");
    // ---- read A1 fragments
    short8v A1h[2], A1l[2];
#pragma unroll
    for (int ks = 0; ks < 2; ++ks) {
      A1h[ks] = *(const short8v*)&P[0 * 16 * KPAD + arow * KPAD + ks * 32 + kq * 8];
      A1l[ks] = *(const short8v*)&P[1 * 16 * KPAD + arow * KPAD + ks * 32 + kq * 8];
    }
    asm volatile("" ::: "memory");
    // ---- matvec1 (per 16-col tile) + residual + relu + restage hn planes
#pragma unroll
    for (int nt = 0; nt < 4; ++nt) {
      int bcol = nt * 16 + arow;
      f32x4 c = {0.f, 0.f, 0.f, 0.f};
#pragma unroll
      for (int ks = 0; ks < 2; ++ks) {
        short8v Bh = *(const short8v*)&Wlds[(0 * 64 + bcol) * 64 + ks * 32 + kq * 8];
        short8v Bl = *(const short8v*)&Wlds[(1 * 64 + bcol) * 64 + ks * 32 + kq * 8];
        c = __builtin_amdgcn_mfma_f32_16x16x32_bf16(A1h[ks], Bh, c, 0, 0, 0);
        c = __builtin_amdgcn_mfma_f32_16x16x32_bf16(A1l[ks], Bh, c, 0, 0, 0);
        c = __builtin_amdgcn_mfma_f32_16x16x32_bf16(A1h[ks], Bl, c, 0, 0, 0);
      }
#pragma unroll
      for (int r = 0; r < 4; ++r) {
        int row = kq * 4 + r;
        int g = base + row;
        float hv = (g < C_N) ? h_con[(size_t)g * H_N + nt * 16 + arow] : 0.f;
        float hn = fmaxf(hv + c[r] + bias[nt], 0.f);
        if (g < C_N) h_con[(size_t)g * H_N + nt * 16 + arow] = hn;
        u16 hi = f2bf(hn);
        u16 lo = f2bf(hn - bf2f(hi));
        P[0 * 16 * KPAD + row * KPAD + nt * 16 + arow] = hi;
        P[1 * 16 * KPAD + row * KPAD + nt * 16 + arow] = lo;
      }
    }
    asm volatile("" ::: "memory");
    // ---- read A2 fragments (hn planes)
    short8v A2h[2], A2l[2];
#pragma unroll
    for (int ks = 0; ks < 2; ++ks) {
      A2h[ks] = *(const short8v*)&P[0 * 16 * KPAD + arow * KPAD + ks * 32 + kq * 8];
      A2l[ks] = *(const short8v*)&P[1 * 16 * KPAD + arow * KPAD + ks * 32 + kq * 8];
    }
    asm volatile("" ::: "memory");
    // ---- matvec2 -> t_bf
#pragma unroll
    for (int nt = 0; nt < 4; ++nt) {
      int bcol = nt * 16 + arow;
      f32x4 c = {0.f, 0.f, 0.f, 0.f};
#pragma unroll
      for (int ks = 0; ks < 2; ++ks) {
        short8v Bh = *(const short8v*)&Wlds[(2 * 64 + bcol) * 64 + ks * 32 + kq * 8];
        short8v Bl = *(const short8v*)&Wlds[(3 * 64 + bcol) * 64 + ks * 32 + kq * 8];
        c = __builtin_amdgcn_mfma_f32_16x16x32_bf16(A2h[ks], Bh, c, 0, 0, 0);
        c = __builtin_amdgcn_mfma_f32_16x16x32_bf16(A2l[ks], Bh, c, 0, 0, 0);
        c = __builtin_amdgcn_mfma_f32_16x16x32_bf16(A2h[ks], Bl, c, 0, 0, 0);
      }
#pragma unroll
      for (int r = 0; r < 4; ++r) {
        int row = kq * 4 + r;
        int g = base + row;
        if (g < C_N) t_out[(size_t)g * H_N + nt * 16 + arow] = f2bf(c[r]);
      }
    }
    asm volatile("" ::: "memory");
  }
}

// ---------------- V-side gather (+ fused score epilogue on last round) ----------

template <int DO_SCORE>
__global__ __launch_bounds__(256) void gather_v_k(const u16* __restrict__ t,
                                                  const int* __restrict__ rs,
                                                  const int* __restrict__ src,
                                                  const float* __restrict__ bias,
                                                  float* __restrict__ h,
                                                  u16* __restrict__ hbf,
                                                  const float* __restrict__ Ws,
                                                  const float* __restrict__ bs,
                                                  float* __restrict__ out) {
  int g = (blockIdx.x * 256 + threadIdx.x) >> 4;
  int lane = threadIdx.x & 15;
  if (g >= V_N) return;
  int s = rs[g], e = rs[g + 1];
  float4 acc = {0.f, 0.f, 0.f, 0.f};
  gather_rows_bf16(t, src, s, e, lane, acc);
  float4 hv = *(const float4*)&h[(size_t)g * H_N + lane * 4];
  float4 b4 = *(const float4*)&bias[lane * 4];
  float4 hn;
  hn.x = fmaxf(hv.x + acc.x + b4.x, 0.f);
  hn.y = fmaxf(hv.y + acc.y + b4.y, 0.f);
  hn.z = fmaxf(hv.z + acc.z + b4.z, 0.f);
  hn.w = fmaxf(hv.w + acc.w + b4.w, 0.f);
  if (DO_SCORE) {
    float4 w = *(const float4*)&Ws[lane * 4];
    float d = hn.x * w.x + hn.y * w.y + hn.z * w.z + hn.w * w.w;
    d += __shfl_down(d, 8, 16);
    d += __shfl_down(d, 4, 16);
    d += __shfl_down(d, 2, 16);
    d += __shfl_down(d, 1, 16);
    if (lane == 0) out[g] = d + bs[0];
  } else {
    *(float4*)&h[(size_t)g * H_N + lane * 4] = hn;
    ushort4 q;
    q.x = f2bf(hn.x); q.y = f2bf(hn.y); q.z = f2bf(hn.z); q.w = f2bf(hn.w);
    *(ushort4*)&hbf[(size_t)g * H_N + lane * 4] = q;
  }
}

// ---------------- launch ----------------

extern "C" void kernel_launch(void* const* d_in, const int* in_sizes, int n_in,
                              void* d_out, int out_size, void* d_ws, size_t ws_size,
                              hipStream_t stream) {
  const float* var_feat = (const float*)d_in[0];
  const float* con_feat = (const float*)d_in[1];
  const float* W_var = (const float*)d_in[2];
  const float* b_var = (const float*)d_in[3];
  const float* W_con = (const float*)d_in[4];
  const float* b_con = (const float*)d_in[5];
  const float* W_v2c = (const float*)d_in[6];
  const float* b_v2c = (const float*)d_in[7];
  const float* W_c2v = (const float*)d_in[8];
  const float* b_c2v = (const float*)d_in[9];
  const float* W_score = (const float*)d_in[10];
  const float* b_score = (const float*)d_in[11];
  const int* var_idx = (const int*)d_in[12];
  const int* constr_idx = (const int*)d_in[13];
  float* out = (float*)d_out;

  char* p = (char*)d_ws;
  auto alloc = [&](size_t bytes) {
    char* r = p;
    p += (bytes + 255) & ~(size_t)255;
    return r;
  };
  float* h_var = (float*)alloc((size_t)V_N * H_N * 4);
  u16* h_var_bf = (u16*)alloc((size_t)V_N * H_N * 2);
  float* h_con = (float*)alloc((size_t)C_N * H_N * 4);
  u16* t_bf = (u16*)alloc((size_t)C_N * H_N * 2);
  u16* wp = (u16*)alloc((size_t)4 * 64 * 64 * 2);
  int* rs_c = (int*)alloc((size_t)(C_N + 1) * 4);
  int* rs_v = (int*)alloc((size_t)(V_N + 1) * 4);
  int* src_c = (int*)alloc((size_t)E_N * 4);
  int* src_v = (int*)alloc((size_t)E_N * 4);
  int* packed_c = (int*)alloc((size_t)E_N * 4);
  int* packed_v = (int*)alloc((size_t)E_N * 4);
  int* ghist_c = (int*)alloc((size_t)NB_C * 4);
  int* ghist_v = (int*)alloc((size_t)NB_V * 4);
  int* base_c = (int*)alloc((size_t)(NB_C + 1) * 4);
  int* base_v = (int*)alloc((size_t)(NB_V + 1) * 4);
  int* cursor_c = (int*)alloc((size_t)NB_C * 4);
  int* cursor_v = (int*)alloc((size_t)NB_V * 4);
  int* tile_ctr = (int*)alloc((size_t)ROUNDS * 4);

  hipMemsetAsync(ghist_c, 0, (size_t)NB_C * 4, stream);
  hipMemsetAsync(ghist_v, 0, (size_t)NB_V * 4, stream);
  hipMemsetAsync(tile_ctr, 0, (size_t)ROUNDS * 4, stream);

  bucket_hist<<<NT, 256, 0, stream>>>(var_idx, constr_idx, ghist_c, ghist_v);
  bucket_scan<<<1, 512, 0, stream>>>(ghist_c, ghist_v, base_c, cursor_c,
                                     base_v, cursor_v, rs_c, rs_v);
  scatter_pack<<<NT, 256, 0, stream>>>(var_idx, constr_idx, cursor_c, cursor_v,
                                       packed_c, packed_v);
  fine_sort<128, C_N><<<NB_C, 256, 0, stream>>>(packed_c, base_c, rs_c, src_c);
  fine_sort<256, V_N><<<NB_V, 256, 0, stream>>>(packed_v, base_v, rs_v, src_v);

  prep_w<<<(H_N * H_N + 255) / 256, 256, 0, stream>>>(W_v2c, W_c2v, wp);

  init_mlp<1><<<(V_N + 15) / 16, 256, 0, stream>>>(var_feat, W_var, b_var, h_var, h_var_bf, V_N);
  init_mlp<0><<<(C_N + 15) / 16, 256, 0, stream>>>(con_feat, W_con, b_con, h_con, nullptr, C_N);

  for (int r = 0; r < ROUNDS; ++r) {
    fused_c<<<FC_BLOCKS, 256, 0, stream>>>(h_var_bf, rs_c, src_c, wp,
                                           b_v2c, h_con, t_bf, &tile_ctr[r]);
    if (r < ROUNDS - 1) {
      gather_v_k<0><<<(V_N + 15) / 16, 256, 0, stream>>>(t_bf, rs_v, src_v, b_c2v, h_var,
                                                         h_var_bf, nullptr, nullptr, nullptr);
    } else {
      gather_v_k<1><<<(V_N + 15) / 16, 256, 0, stream>>>(t_bf, rs_v, src_v, b_c2v, h_var,
                                                         nullptr, W_score, b_score, out);
    }
  }
}

// Round 12
// 296.263 us; speedup vs baseline: 1.6195x; 1.6195x over previous
//
#include <hip/hip_runtime.h>

typedef unsigned short u16;
typedef unsigned int u32;
typedef __attribute__((ext_vector_type(8))) short short8v;   // 8 bf16 (4 VGPRs)
typedef __attribute__((ext_vector_type(4))) float f32x4;

#define V_N 100000
#define C_N 50000
#define E_N 1250000
#define VF_N 32
#define H_N 64
#define ROUNDS 3

#define TILE 4096
#define NT ((E_N + TILE - 1) / TILE)      // 306 edge tiles
#define NB_C ((C_N + 127) / 128)          // 391 coarse buckets (128 dests each)
#define NB_V ((V_N + 255) / 256)          // 391 coarse buckets (256 dests each)
#define KPAD 72                           // plane row stride in u16 elements
#define NTILES_C ((C_N + 15) / 16)        // 3125 dest tiles (exactly 16*3125=50000)
#define FC_WAVES 8
#define FC_BLOCKS ((NTILES_C + FC_WAVES - 1) / FC_WAVES)   // 391 blocks, all resident

static __device__ __forceinline__ float bf2f(u16 x) {
  return __uint_as_float(((u32)x) << 16);
}
static __device__ __forceinline__ u16 f2bf(float f) {
  u32 u = __float_as_uint(f);
  u32 r = (u + 0x7fff + ((u >> 16) & 1)) >> 16;  // RNE
  return (u16)r;
}

// ---------------- CSR build: two-level bucket sort, block-aggregated atomics ----

__global__ __launch_bounds__(256) void bucket_hist(const int* __restrict__ vi,
                                                   const int* __restrict__ ci,
                                                   int* __restrict__ gh_c,
                                                   int* __restrict__ gh_v) {
  __shared__ int hc[NB_C], hv[NB_V];
  int t = threadIdx.x;
  for (int j = t; j < NB_C; j += 256) hc[j] = 0;
  for (int j = t; j < NB_V; j += 256) hv[j] = 0;
  __syncthreads();
  int base = blockIdx.x * TILE;
#pragma unroll
  for (int i = 0; i < 16; ++i) {
    int idx = base + i * 256 + t;
    if (idx < E_N) {
      atomicAdd(&hc[ci[idx] >> 7], 1);
      atomicAdd(&hv[vi[idx] >> 8], 1);
    }
  }
  __syncthreads();
  for (int j = t; j < NB_C; j += 256) if (hc[j]) atomicAdd(&gh_c[j], hc[j]);
  for (int j = t; j < NB_V; j += 256) if (hv[j]) atomicAdd(&gh_v[j], hv[j]);
}

__global__ __launch_bounds__(512) void bucket_scan(const int* __restrict__ gh_c,
                                                   const int* __restrict__ gh_v,
                                                   int* __restrict__ base_c,
                                                   int* __restrict__ cursor_c,
                                                   int* __restrict__ base_v,
                                                   int* __restrict__ cursor_v,
                                                   int* __restrict__ rs_c,
                                                   int* __restrict__ rs_v) {
  __shared__ int lds[512];
  int t = threadIdx.x;
  int x = (t < NB_C) ? gh_c[t] : 0;
  lds[t] = x;
  __syncthreads();
  for (int off = 1; off < 512; off <<= 1) {
    int v = (t >= off) ? lds[t - off] : 0;
    __syncthreads();
    lds[t] += v;
    __syncthreads();
  }
  int excl = lds[t] - x;
  if (t < NB_C) { base_c[t] = excl; cursor_c[t] = excl; }
  if (t == 511) base_c[NB_C] = lds[511];
  __syncthreads();
  int y = (t < NB_V) ? gh_v[t] : 0;
  lds[t] = y;
  __syncthreads();
  for (int off = 1; off < 512; off <<= 1) {
    int v = (t >= off) ? lds[t - off] : 0;
    __syncthreads();
    lds[t] += v;
    __syncthreads();
  }
  int excl2 = lds[t] - y;
  if (t < NB_V) { base_v[t] = excl2; cursor_v[t] = excl2; }
  if (t == 511) base_v[NB_V] = lds[511];
  if (t == 0) { rs_c[C_N] = E_N; rs_v[V_N] = E_N; }
}

// Packed element: (local_dest << 17) | src_id   (src < 2^17, local_dest <= 255)
__global__ __launch_bounds__(256) void scatter_pack(const int* __restrict__ vi,
                                                    const int* __restrict__ ci,
                                                    int* __restrict__ cursor_c,
                                                    int* __restrict__ cursor_v,
                                                    int* __restrict__ packed_c,
                                                    int* __restrict__ packed_v) {
  __shared__ int hc[NB_C], hv[NB_V], sc[NB_C], sv[NB_V];
  int t = threadIdx.x;
  for (int j = t; j < NB_C; j += 256) hc[j] = 0;
  for (int j = t; j < NB_V; j += 256) hv[j] = 0;
  __syncthreads();
  int base = blockIdx.x * TILE;
  int cc[16], vv[16];
#pragma unroll
  for (int i = 0; i < 16; ++i) {
    int idx = base + i * 256 + t;
    if (idx < E_N) {
      cc[i] = ci[idx];
      vv[i] = vi[idx];
      atomicAdd(&hc[cc[i] >> 7], 1);
      atomicAdd(&hv[vv[i] >> 8], 1);
    } else {
      cc[i] = -1;
      vv[i] = -1;
    }
  }
  __syncthreads();
  for (int j = t; j < NB_C; j += 256) {
    int n = hc[j];
    if (n > 0) sc[j] = atomicAdd(&cursor_c[j], n);
    hc[j] = 0;
  }
  for (int j = t; j < NB_V; j += 256) {
    int n = hv[j];
    if (n > 0) sv[j] = atomicAdd(&cursor_v[j], n);
    hv[j] = 0;
  }
  __syncthreads();
#pragma unroll
  for (int i = 0; i < 16; ++i) {
    if (cc[i] >= 0) {
      int b = cc[i] >> 7;
      int r = atomicAdd(&hc[b], 1);
      packed_c[sc[b] + r] = ((cc[i] & 127) << 17) | vv[i];
      int b2 = vv[i] >> 8;
      int r2 = atomicAdd(&hv[b2], 1);
      packed_v[sv[b2] + r2] = ((vv[i] & 255) << 17) | cc[i];
    }
  }
}

template <int LOCAL_N, int N_DEST>
__global__ __launch_bounds__(256) void fine_sort(const int* __restrict__ packed,
                                                 const int* __restrict__ base,
                                                 int* __restrict__ rs,
                                                 int* __restrict__ srco) {
  __shared__ int cnt[LOCAL_N];
  __shared__ int excl[LOCAL_N];
  int b = blockIdx.x, t = threadIdx.x;
  int s0 = base[b], s1 = base[b + 1];
  if (t < LOCAL_N) cnt[t] = 0;
  __syncthreads();
  for (int i = s0 + t; i < s1; i += 256) atomicAdd(&cnt[packed[i] >> 17], 1);
  __syncthreads();
  if (t == 0) {
    int run = 0;
    for (int k = 0; k < LOCAL_N; ++k) { excl[k] = run; run += cnt[k]; }
  }
  __syncthreads();
  if (t < LOCAL_N) {
    int d = b * LOCAL_N + t;
    if (d < N_DEST) rs[d] = s0 + excl[t];
    cnt[t] = excl[t];
  }
  __syncthreads();
  for (int i = s0 + t; i < s1; i += 256) {
    int w = packed[i];
    int ld = w >> 17;
    int pos = s0 + atomicAdd(&cnt[ld], 1);
    srco[pos] = w & 0x1FFFF;
  }
}

// ---------------- W prep: split W1,W2 into bf16 hi/lo planes, transposed [col][k]

__global__ __launch_bounds__(256) void prep_w(const float* __restrict__ W1,
                                              const float* __restrict__ W2,
                                              u16* __restrict__ wp) {
  int i = blockIdx.x * 256 + threadIdx.x;
  if (i >= H_N * H_N) return;
  int k = i >> 6, n = i & 63;
  float w1 = W1[i];
  u16 h1 = f2bf(w1);
  u16 l1 = f2bf(w1 - bf2f(h1));
  wp[(0 * 64 + n) * 64 + k] = h1;       // mat0 hi
  wp[(1 * 64 + n) * 64 + k] = l1;       // mat0 lo
  float w2 = W2[i];
  u16 h2 = f2bf(w2);
  u16 l2 = f2bf(w2 - bf2f(h2));
  wp[(2 * 64 + n) * 64 + k] = h2;       // mat1 hi
  wp[(3 * 64 + n) * 64 + k] = l2;       // mat1 lo
}

// ---------------- input MLP: h = relu(feat[n,32] @ W[32,64] + b) ----------------

template <int WRITE_BF>
__global__ __launch_bounds__(256) void init_mlp(const float* __restrict__ feat,
                                                const float* __restrict__ W,
                                                const float* __restrict__ b,
                                                float* __restrict__ h,
                                                u16* __restrict__ hbf, int n) {
  __shared__ float Wl[VF_N * H_N];
  for (int i = threadIdx.x; i < VF_N * H_N; i += 256) Wl[i] = W[i];
  __syncthreads();
  int g = (blockIdx.x * 256 + threadIdx.x) >> 4;
  int lane = threadIdx.x & 15;
  if (g >= n) return;
  float2 rv = *(const float2*)&feat[(size_t)g * VF_N + lane * 2];
  float4 acc = *(const float4*)&b[lane * 4];
#pragma unroll
  for (int k = 0; k < VF_N; ++k) {
    float el = (k & 1) ? rv.y : rv.x;
    float v = __shfl(el, k >> 1, 16);
    float4 w = *(const float4*)&Wl[k * H_N + lane * 4];
    acc.x += v * w.x; acc.y += v * w.y; acc.z += v * w.z; acc.w += v * w.w;
  }
  acc.x = fmaxf(acc.x, 0.f); acc.y = fmaxf(acc.y, 0.f);
  acc.z = fmaxf(acc.z, 0.f); acc.w = fmaxf(acc.w, 0.f);
  *(float4*)&h[(size_t)g * H_N + lane * 4] = acc;
  if (WRITE_BF) {
    ushort4 q;
    q.x = f2bf(acc.x); q.y = f2bf(acc.y); q.z = f2bf(acc.z); q.w = f2bf(acc.w);
    *(ushort4*)&hbf[(size_t)g * H_N + lane * 4] = q;
  }
}

// ---------------- batched bf16 row gather (8B/lane, 16 deep, 32-VGPR buffer) ---

static __device__ __forceinline__ void gather_rows_bf16(const u16* __restrict__ tbl,
                                                        const int* __restrict__ src,
                                                        int s, int e, int lane,
                                                        float4& acc) {
  int p = s;
  for (; p + 16 <= e; p += 16) {
    int myidx = src[p + lane];
    ushort4 vv[16];
#pragma unroll
    for (int j = 0; j < 16; ++j) {
      int sj = __shfl(myidx, j, 16);
      vv[j] = *(const ushort4*)&tbl[(size_t)sj * H_N + lane * 4];
    }
#pragma unroll
    for (int j = 0; j < 16; ++j) {
      acc.x += bf2f(vv[j].x); acc.y += bf2f(vv[j].y);
      acc.z += bf2f(vv[j].z); acc.w += bf2f(vv[j].w);
    }
  }
  if (p < e) {
    int cnt = e - p;
    int myidx = (lane < cnt) ? src[p + lane] : 0;
    ushort4 vv[16];
#pragma unroll
    for (int j = 0; j < 16; ++j) {
      int sj = __shfl(myidx, j, 16);
      vv[j] = *(const ushort4*)&tbl[(size_t)sj * H_N + lane * 4];
    }
#pragma unroll
    for (int j = 0; j < 16; ++j) {
      if (j < cnt) {
        acc.x += bf2f(vv[j].x); acc.y += bf2f(vv[j].y);
        acc.z += bf2f(vv[j].z); acc.w += bf2f(vv[j].w);
      }
    }
  }
}

// ---------------- fused C-side update (8 waves/block, 1 tile/wave, static) -----
//   s      = segsum_c(h_var_bf)                (bf16 gather, fp32 accumulate)
//   h_con  = relu(h_con + s @ W1 + b1)         (MFMA, hi/lo compensated)
//   t_bf   = bf16(h_con @ W2)                  (MFMA, hi/lo compensated)
// Scheduling lessons: round-9 static 4-wave blocks left 53 waves with 2 tiles
// (17us tail, occ 16.7%); round-10/11 single-address atomic queue serialized
// ~6200 device atomics (~50us, VALUBusy 10%). This round: 391 blocks x 8 waves
// = 3128 slots >= 3125 tiles, ALL blocks co-resident, each wave exactly <=1
// tile. Per-wave LDS staging halved to ONE plane (hi then lo, two passes) to
// fit 8 waves in the same 51.2KB block footprint.

__global__ __launch_bounds__(512) void fused_c(const u16* __restrict__ h_var_bf,
                                               const int* __restrict__ rs,
                                               const int* __restrict__ src,
                                               const u16* __restrict__ wp,
                                               const float* __restrict__ b1g,
                                               float* __restrict__ h_con,
                                               u16* __restrict__ t_out) {
  __shared__ u16 Wlds[4 * 64 * 64];              // 32768 B: [mat*2+pl][col][k]
  __shared__ u16 Aplane[FC_WAVES][16 * KPAD];    // 8 waves x 2304 B, hi/lo reused

  for (int i = threadIdx.x; i < 4 * 64 * 64 / 2; i += 512)
    ((u32*)Wlds)[i] = ((const u32*)wp)[i];
  __syncthreads();

  int lane64 = threadIdx.x & 63;
  int wave = threadIdx.x >> 6;
  int lane = threadIdx.x & 15;
  int grp = (threadIdx.x >> 4) & 3;
  int arow = lane64 & 15;     // A row / D col (within tile)
  int kq = lane64 >> 4;       // k-octet selector / D row-quad
  u16* P = &Aplane[wave][0];

  int tile = blockIdx.x * FC_WAVES + wave;
  if (tile >= NTILES_C) return;
  int base = tile * 16;

  float bias[4];
#pragma unroll
  for (int nt = 0; nt < 4; ++nt) bias[nt] = b1g[nt * 16 + arow];

  // ---- gather all 4 of this group's rows; keep sums in registers
  float4 accs[4];
#pragma unroll
  for (int q = 0; q < 4; ++q) {
    int row = 4 * q + grp;
    int g = base + row;
    float4 a = {0.f, 0.f, 0.f, 0.f};
    if (g < C_N) gather_rows_bf16(h_var_bf, src, rs[g], rs[g + 1], lane, a);
    accs[q] = a;
  }
  // ---- pass 1: stage hi plane, read A1h
#pragma unroll
  for (int q = 0; q < 4; ++q) {
    int row = 4 * q + grp;
    ushort4 qh;
    qh.x = f2bf(accs[q].x); qh.y = f2bf(accs[q].y);
    qh.z = f2bf(accs[q].z); qh.w = f2bf(accs[q].w);
    *(ushort4*)&P[row * KPAD + lane * 4] = qh;
  }
  asm volatile("" ::: "memory");
  short8v A1h[2];
#pragma unroll
  for (int ks = 0; ks < 2; ++ks)
    A1h[ks] = *(const short8v*)&P[arow * KPAD + ks * 32 + kq * 8];
  asm volatile("" ::: "memory");
  // ---- pass 2: stage lo plane (overwrite), read A1l
#pragma unroll
  for (int q = 0; q < 4; ++q) {
    int row = 4 * q + grp;
    ushort4 ql;
    ql.x = f2bf(accs[q].x - bf2f(f2bf(accs[q].x)));
    ql.y = f2bf(accs[q].y - bf2f(f2bf(accs[q].y)));
    ql.z = f2bf(accs[q].z - bf2f(f2bf(accs[q].z)));
    ql.w = f2bf(accs[q].w - bf2f(f2bf(accs[q].w)));
    *(ushort4*)&P[row * KPAD + lane * 4] = ql;
  }
  asm volatile("" ::: "memory");
  short8v A1l[2];
#pragma unroll
  for (int ks = 0; ks < 2; ++ks)
    A1l[ks] = *(const short8v*)&P[arow * KPAD + ks * 32 + kq * 8];
  asm volatile("" ::: "memory");
  // ---- matvec1 + residual + relu; keep hn in regs
  float hn[4][4];  // [nt][r]
#pragma unroll
  for (int nt = 0; nt < 4; ++nt) {
    int bcol = nt * 16 + arow;
    f32x4 c = {0.f, 0.f, 0.f, 0.f};
#pragma unroll
    for (int ks = 0; ks < 2; ++ks) {
      short8v Bh = *(const short8v*)&Wlds[(0 * 64 + bcol) * 64 + ks * 32 + kq * 8];
      short8v Bl = *(const short8v*)&Wlds[(1 * 64 + bcol) * 64 + ks * 32 + kq * 8];
      c = __builtin_amdgcn_mfma_f32_16x16x32_bf16(A1h[ks], Bh, c, 0, 0, 0);
      c = __builtin_amdgcn_mfma_f32_16x16x32_bf16(A1l[ks], Bh, c, 0, 0, 0);
      c = __builtin_amdgcn_mfma_f32_16x16x32_bf16(A1h[ks], Bl, c, 0, 0, 0);
    }
#pragma unroll
    for (int r = 0; r < 4; ++r) {
      int row = kq * 4 + r;
      int g = base + row;
      float hv = (g < C_N) ? h_con[(size_t)g * H_N + nt * 16 + arow] : 0.f;
      float v = fmaxf(hv + c[r] + bias[nt], 0.f);
      if (g < C_N) h_con[(size_t)g * H_N + nt * 16 + arow] = v;
      hn[nt][r] = v;
    }
  }
  // ---- pass 1: stage hn hi plane, read A2h
#pragma unroll
  for (int nt = 0; nt < 4; ++nt)
#pragma unroll
    for (int r = 0; r < 4; ++r)
      P[(kq * 4 + r) * KPAD + nt * 16 + arow] = f2bf(hn[nt][r]);
  asm volatile("" ::: "memory");
  short8v A2h[2];
#pragma unroll
  for (int ks = 0; ks < 2; ++ks)
    A2h[ks] = *(const short8v*)&P[arow * KPAD + ks * 32 + kq * 8];
  asm volatile("" ::: "memory");
  // ---- pass 2: stage hn lo plane, read A2l
#pragma unroll
  for (int nt = 0; nt < 4; ++nt)
#pragma unroll
    for (int r = 0; r < 4; ++r) {
      u16 hi = f2bf(hn[nt][r]);
      P[(kq * 4 + r) * KPAD + nt * 16 + arow] = f2bf(hn[nt][r] - bf2f(hi));
    }
  asm volatile("" ::: "memory");
  short8v A2l[2];
#pragma unroll
  for (int ks = 0; ks < 2; ++ks)
    A2l[ks] = *(const short8v*)&P[arow * KPAD + ks * 32 + kq * 8];
  asm volatile("" ::: "memory");
  // ---- matvec2 -> t_bf
#pragma unroll
  for (int nt = 0; nt < 4; ++nt) {
    int bcol = nt * 16 + arow;
    f32x4 c = {0.f, 0.f, 0.f, 0.f};
#pragma unroll
    for (int ks = 0; ks < 2; ++ks) {
      short8v Bh = *(const short8v*)&Wlds[(2 * 64 + bcol) * 64 + ks * 32 + kq * 8];
      short8v Bl = *(const short8v*)&Wlds[(3 * 64 + bcol) * 64 + ks * 32 + kq * 8];
      c = __builtin_amdgcn_mfma_f32_16x16x32_bf16(A2h[ks], Bh, c, 0, 0, 0);
      c = __builtin_amdgcn_mfma_f32_16x16x32_bf16(A2l[ks], Bh, c, 0, 0, 0);
      c = __builtin_amdgcn_mfma_f32_16x16x32_bf16(A2h[ks], Bl, c, 0, 0, 0);
    }
#pragma unroll
    for (int r = 0; r < 4; ++r) {
      int row = kq * 4 + r;
      int g = base + row;
      if (g < C_N) t_out[(size_t)g * H_N + nt * 16 + arow] = f2bf(c[r]);
    }
  }
}

// ---------------- V-side gather (+ fused score epilogue on last round) ----------

template <int DO_SCORE>
__global__ __launch_bounds__(256) void gather_v_k(const u16* __restrict__ t,
                                                  const int* __restrict__ rs,
                                                  const int* __restrict__ src,
                                                  const float* __restrict__ bias,
                                                  float* __restrict__ h,
                                                  u16* __restrict__ hbf,
                                                  const float* __restrict__ Ws,
                                                  const float* __restrict__ bs,
                                                  float* __restrict__ out) {
  int g = (blockIdx.x * 256 + threadIdx.x) >> 4;
  int lane = threadIdx.x & 15;
  if (g >= V_N) return;
  int s = rs[g], e = rs[g + 1];
  float4 acc = {0.f, 0.f, 0.f, 0.f};
  gather_rows_bf16(t, src, s, e, lane, acc);
  float4 hv = *(const float4*)&h[(size_t)g * H_N + lane * 4];
  float4 b4 = *(const float4*)&bias[lane * 4];
  float4 hn;
  hn.x = fmaxf(hv.x + acc.x + b4.x, 0.f);
  hn.y = fmaxf(hv.y + acc.y + b4.y, 0.f);
  hn.z = fmaxf(hv.z + acc.z + b4.z, 0.f);
  hn.w = fmaxf(hv.w + acc.w + b4.w, 0.f);
  if (DO_SCORE) {
    float4 w = *(const float4*)&Ws[lane * 4];
    float d = hn.x * w.x + hn.y * w.y + hn.z * w.z + hn.w * w.w;
    d += __shfl_down(d, 8, 16);
    d += __shfl_down(d, 4, 16);
    d += __shfl_down(d, 2, 16);
    d += __shfl_down(d, 1, 16);
    if (lane == 0) out[g] = d + bs[0];
  } else {
    *(float4*)&h[(size_t)g * H_N + lane * 4] = hn;
    ushort4 q;
    q.x = f2bf(hn.x); q.y = f2bf(hn.y); q.z = f2bf(hn.z); q.w = f2bf(hn.w);
    *(ushort4*)&hbf[(size_t)g * H_N + lane * 4] = q;
  }
}

// ---------------- launch ----------------

extern "C" void kernel_launch(void* const* d_in, const int* in_sizes, int n_in,
                              void* d_out, int out_size, void* d_ws, size_t ws_size,
                              hipStream_t stream) {
  const float* var_feat = (const float*)d_in[0];
  const float* con_feat = (const float*)d_in[1];
  const float* W_var = (const float*)d_in[2];
  const float* b_var = (const float*)d_in[3];
  const float* W_con = (const float*)d_in[4];
  const float* b_con = (const float*)d_in[5];
  const float* W_v2c = (const float*)d_in[6];
  const float* b_v2c = (const float*)d_in[7];
  const float* W_c2v = (const float*)d_in[8];
  const float* b_c2v = (const float*)d_in[9];
  const float* W_score = (const float*)d_in[10];
  const float* b_score = (const float*)d_in[11];
  const int* var_idx = (const int*)d_in[12];
  const int* constr_idx = (const int*)d_in[13];
  float* out = (float*)d_out;

  char* p = (char*)d_ws;
  auto alloc = [&](size_t bytes) {
    char* r = p;
    p += (bytes + 255) & ~(size_t)255;
    return r;
  };
  float* h_var = (float*)alloc((size_t)V_N * H_N * 4);
  u16* h_var_bf = (u16*)alloc((size_t)V_N * H_N * 2);
  float* h_con = (float*)alloc((size_t)C_N * H_N * 4);
  u16* t_bf = (u16*)alloc((size_t)C_N * H_N * 2);
  u16* wp = (u16*)alloc((size_t)4 * 64 * 64 * 2);
  int* rs_c = (int*)alloc((size_t)(C_N + 1) * 4);
  int* rs_v = (int*)alloc((size_t)(V_N + 1) * 4);
  int* src_c = (int*)alloc((size_t)E_N * 4);
  int* src_v = (int*)alloc((size_t)E_N * 4);
  int* packed_c = (int*)alloc((size_t)E_N * 4);
  int* packed_v = (int*)alloc((size_t)E_N * 4);
  int* ghist_c = (int*)alloc((size_t)NB_C * 4);
  int* ghist_v = (int*)alloc((size_t)NB_V * 4);
  int* base_c = (int*)alloc((size_t)(NB_C + 1) * 4);
  int* base_v = (int*)alloc((size_t)(NB_V + 1) * 4);
  int* cursor_c = (int*)alloc((size_t)NB_C * 4);
  int* cursor_v = (int*)alloc((size_t)NB_V * 4);

  hipMemsetAsync(ghist_c, 0, (size_t)NB_C * 4, stream);
  hipMemsetAsync(ghist_v, 0, (size_t)NB_V * 4, stream);

  bucket_hist<<<NT, 256, 0, stream>>>(var_idx, constr_idx, ghist_c, ghist_v);
  bucket_scan<<<1, 512, 0, stream>>>(ghist_c, ghist_v, base_c, cursor_c,
                                     base_v, cursor_v, rs_c, rs_v);
  scatter_pack<<<NT, 256, 0, stream>>>(var_idx, constr_idx, cursor_c, cursor_v,
                                       packed_c, packed_v);
  fine_sort<128, C_N><<<NB_C, 256, 0, stream>>>(packed_c, base_c, rs_c, src_c);
  fine_sort<256, V_N><<<NB_V, 256, 0, stream>>>(packed_v, base_v, rs_v, src_v);

  prep_w<<<(H_N * H_N + 255) / 256, 256, 0, stream>>>(W_v2c, W_c2v, wp);

  init_mlp<1><<<(V_N + 15) / 16, 256, 0, stream>>>(var_feat, W_var, b_var, h_var, h_var_bf, V_N);
  init_mlp<0><<<(C_N + 15) / 16, 256, 0, stream>>>(con_feat, W_con, b_con, h_con, nullptr, C_N);

  for (int r = 0; r < ROUNDS; ++r) {
    fused_c<<<FC_BLOCKS, 512, 0, stream>>>(h_var_bf, rs_c, src_c, wp,
                                           b_v2c, h_con, t_bf);
    if (r < ROUNDS - 1) {
      gather_v_k<0><<<(V_N + 15) / 16, 256, 0, stream>>>(t_bf, rs_v, src_v, b_c2v, h_var,
                                                         h_var_bf, nullptr, nullptr, nullptr);
    } else {
      gather_v_k<1><<<(V_N + 15) / 16, 256, 0, stream>>>(t_bf, rs_v, src_v, b_c2v, h_var,
                                                         nullptr, W_score, b_score, out);
    }
  }
}

// Round 13
// 282.763 us; speedup vs baseline: 1.6968x; 1.0477x over previous
//
#include <hip/hip_runtime.h>

typedef unsigned short u16;
typedef unsigned int u32;
typedef __attribute__((ext_vector_type(8))) short short8v;   // 8 bf16 (4 VGPRs)
typedef __attribute__((ext_vector_type(4))) float f32x4;

#define V_N 100000
#define C_N 50000
#define E_N 1250000
#define VF_N 32
#define H_N 64
#define ROUNDS 3

#define TILE 4096
#define NT ((E_N + TILE - 1) / TILE)      // 306 edge tiles
#define NB_C ((C_N + 127) / 128)          // 391 coarse buckets (128 dests each)
#define NB_V ((V_N + 255) / 256)          // 391 coarse buckets (256 dests each)
#define KPAD 72                           // plane row stride in u16 elements
#define NTILES_C ((C_N + 15) / 16)        // 3125 dest tiles
#define FC_WAVES 8
#define FC_BLOCKS ((NTILES_C + FC_WAVES - 1) / FC_WAVES)   // 391 blocks, all resident
#define MLP_NB_V ((V_N + 15) / 16)        // 6250
#define MLP_NB_C ((C_N + 15) / 16)        // 3125

static __device__ __forceinline__ float bf2f(u16 x) {
  return __uint_as_float(((u32)x) << 16);
}
static __device__ __forceinline__ u16 f2bf(float f) {
  u32 u = __float_as_uint(f);
  u32 r = (u + 0x7fff + ((u >> 16) & 1)) >> 16;  // RNE
  return (u16)r;
}

// ---------------- CSR build: two-level bucket sort, block-aggregated atomics ----

__global__ __launch_bounds__(256) void bucket_hist(const int* __restrict__ vi,
                                                   const int* __restrict__ ci,
                                                   int* __restrict__ gh_c,
                                                   int* __restrict__ gh_v) {
  __shared__ int hc[NB_C], hv[NB_V];
  int t = threadIdx.x;
  for (int j = t; j < NB_C; j += 256) hc[j] = 0;
  for (int j = t; j < NB_V; j += 256) hv[j] = 0;
  __syncthreads();
  int base = blockIdx.x * TILE;
#pragma unroll
  for (int i = 0; i < 16; ++i) {
    int idx = base + i * 256 + t;
    if (idx < E_N) {
      atomicAdd(&hc[ci[idx] >> 7], 1);
      atomicAdd(&hv[vi[idx] >> 8], 1);
    }
  }
  __syncthreads();
  for (int j = t; j < NB_C; j += 256) if (hc[j]) atomicAdd(&gh_c[j], hc[j]);
  for (int j = t; j < NB_V; j += 256) if (hv[j]) atomicAdd(&gh_v[j], hv[j]);
}

__global__ __launch_bounds__(512) void bucket_scan(const int* __restrict__ gh_c,
                                                   const int* __restrict__ gh_v,
                                                   int* __restrict__ base_c,
                                                   int* __restrict__ cursor_c,
                                                   int* __restrict__ base_v,
                                                   int* __restrict__ cursor_v,
                                                   int* __restrict__ rs_c,
                                                   int* __restrict__ rs_v) {
  __shared__ int lds[512];
  int t = threadIdx.x;
  int x = (t < NB_C) ? gh_c[t] : 0;
  lds[t] = x;
  __syncthreads();
  for (int off = 1; off < 512; off <<= 1) {
    int v = (t >= off) ? lds[t - off] : 0;
    __syncthreads();
    lds[t] += v;
    __syncthreads();
  }
  int excl = lds[t] - x;
  if (t < NB_C) { base_c[t] = excl; cursor_c[t] = excl; }
  if (t == 511) base_c[NB_C] = lds[511];
  __syncthreads();
  int y = (t < NB_V) ? gh_v[t] : 0;
  lds[t] = y;
  __syncthreads();
  for (int off = 1; off < 512; off <<= 1) {
    int v = (t >= off) ? lds[t - off] : 0;
    __syncthreads();
    lds[t] += v;
    __syncthreads();
  }
  int excl2 = lds[t] - y;
  if (t < NB_V) { base_v[t] = excl2; cursor_v[t] = excl2; }
  if (t == 511) base_v[NB_V] = lds[511];
  if (t == 0) { rs_c[C_N] = E_N; rs_v[V_N] = E_N; }
}

// Packed element: (local_dest << 17) | src_id   (src < 2^17, local_dest <= 255)
__global__ __launch_bounds__(256) void scatter_pack(const int* __restrict__ vi,
                                                    const int* __restrict__ ci,
                                                    int* __restrict__ cursor_c,
                                                    int* __restrict__ cursor_v,
                                                    int* __restrict__ packed_c,
                                                    int* __restrict__ packed_v) {
  __shared__ int hc[NB_C], hv[NB_V], sc[NB_C], sv[NB_V];
  int t = threadIdx.x;
  for (int j = t; j < NB_C; j += 256) hc[j] = 0;
  for (int j = t; j < NB_V; j += 256) hv[j] = 0;
  __syncthreads();
  int base = blockIdx.x * TILE;
  int cc[16], vv[16];
#pragma unroll
  for (int i = 0; i < 16; ++i) {
    int idx = base + i * 256 + t;
    if (idx < E_N) {
      cc[i] = ci[idx];
      vv[i] = vi[idx];
      atomicAdd(&hc[cc[i] >> 7], 1);
      atomicAdd(&hv[vv[i] >> 8], 1);
    } else {
      cc[i] = -1;
      vv[i] = -1;
    }
  }
  __syncthreads();
  for (int j = t; j < NB_C; j += 256) {
    int n = hc[j];
    if (n > 0) sc[j] = atomicAdd(&cursor_c[j], n);
    hc[j] = 0;
  }
  for (int j = t; j < NB_V; j += 256) {
    int n = hv[j];
    if (n > 0) sv[j] = atomicAdd(&cursor_v[j], n);
    hv[j] = 0;
  }
  __syncthreads();
#pragma unroll
  for (int i = 0; i < 16; ++i) {
    if (cc[i] >= 0) {
      int b = cc[i] >> 7;
      int r = atomicAdd(&hc[b], 1);
      packed_c[sc[b] + r] = ((cc[i] & 127) << 17) | vv[i];
      int b2 = vv[i] >> 8;
      int r2 = atomicAdd(&hv[b2], 1);
      packed_v[sv[b2] + r2] = ((vv[i] & 255) << 17) | cc[i];
    }
  }
}

// Merged per-bucket counting sort for BOTH sides (one launch, 782 blocks).
__global__ __launch_bounds__(256) void fine_sort_both(const int* __restrict__ packed_c,
                                                      const int* __restrict__ base_c,
                                                      int* __restrict__ rs_c,
                                                      int* __restrict__ src_c,
                                                      const int* __restrict__ packed_v,
                                                      const int* __restrict__ base_v,
                                                      int* __restrict__ rs_v,
                                                      int* __restrict__ src_v) {
  __shared__ int cnt[256];
  __shared__ int excl[256];
  int blk = blockIdx.x, t = threadIdx.x;
  const int* packed;
  const int* base;
  int* rs;
  int* srco;
  int LOCAL_N, N_DEST, b;
  if (blk < NB_C) {
    packed = packed_c; base = base_c; rs = rs_c; srco = src_c;
    LOCAL_N = 128; N_DEST = C_N; b = blk;
  } else {
    packed = packed_v; base = base_v; rs = rs_v; srco = src_v;
    LOCAL_N = 256; N_DEST = V_N; b = blk - NB_C;
  }
  int s0 = base[b], s1 = base[b + 1];
  if (t < LOCAL_N) cnt[t] = 0;
  __syncthreads();
  for (int i = s0 + t; i < s1; i += 256) atomicAdd(&cnt[packed[i] >> 17], 1);
  __syncthreads();
  if (t == 0) {
    int run = 0;
    for (int k = 0; k < LOCAL_N; ++k) { excl[k] = run; run += cnt[k]; }
  }
  __syncthreads();
  if (t < LOCAL_N) {
    int d = b * LOCAL_N + t;
    if (d < N_DEST) rs[d] = s0 + excl[t];
    cnt[t] = excl[t];
  }
  __syncthreads();
  for (int i = s0 + t; i < s1; i += 256) {
    int w = packed[i];
    int ld = w >> 17;
    int pos = s0 + atomicAdd(&cnt[ld], 1);
    srco[pos] = w & 0x1FFFF;
  }
}

// ---------------- merged init: var MLP + con MLP + weight prep (one launch) ----
// blocks [0, MLP_NB_V): var rows; [MLP_NB_V, +MLP_NB_C): con rows; last 16: prep_w.

__global__ __launch_bounds__(256) void init_all(const float* __restrict__ var_feat,
                                                const float* __restrict__ W_var,
                                                const float* __restrict__ b_var,
                                                float* __restrict__ h_var,
                                                u16* __restrict__ h_var_bf,
                                                const float* __restrict__ con_feat,
                                                const float* __restrict__ W_con,
                                                const float* __restrict__ b_con,
                                                float* __restrict__ h_con,
                                                const float* __restrict__ W1,
                                                const float* __restrict__ W2,
                                                u16* __restrict__ wp) {
  int blk = blockIdx.x;
  if (blk >= MLP_NB_V + MLP_NB_C) {
    // ---- prep_w: split W1,W2 into bf16 hi/lo planes, transposed [col][k]
    int i = (blk - MLP_NB_V - MLP_NB_C) * 256 + threadIdx.x;
    if (i >= H_N * H_N) return;
    int k = i >> 6, n = i & 63;
    float w1 = W1[i];
    u16 h1 = f2bf(w1);
    u16 l1 = f2bf(w1 - bf2f(h1));
    wp[(0 * 64 + n) * 64 + k] = h1;
    wp[(1 * 64 + n) * 64 + k] = l1;
    float w2 = W2[i];
    u16 h2 = f2bf(w2);
    u16 l2 = f2bf(w2 - bf2f(h2));
    wp[(2 * 64 + n) * 64 + k] = h2;
    wp[(3 * 64 + n) * 64 + k] = l2;
    return;
  }
  int is_var = (blk < MLP_NB_V);
  const float* feat = is_var ? var_feat : con_feat;
  const float* W = is_var ? W_var : W_con;
  const float* b = is_var ? b_var : b_con;
  float* h = is_var ? h_var : h_con;
  int n = is_var ? V_N : C_N;
  int gbase = (is_var ? blk : (blk - MLP_NB_V)) * 16;

  __shared__ float Wl[VF_N * H_N];
  for (int i = threadIdx.x; i < VF_N * H_N; i += 256) Wl[i] = W[i];
  __syncthreads();
  int g = gbase + (threadIdx.x >> 4);
  int lane = threadIdx.x & 15;
  if (g >= n) return;
  float2 rv = *(const float2*)&feat[(size_t)g * VF_N + lane * 2];
  float4 acc = *(const float4*)&b[lane * 4];
#pragma unroll
  for (int k = 0; k < VF_N; ++k) {
    float el = (k & 1) ? rv.y : rv.x;
    float v = __shfl(el, k >> 1, 16);
    float4 w = *(const float4*)&Wl[k * H_N + lane * 4];
    acc.x += v * w.x; acc.y += v * w.y; acc.z += v * w.z; acc.w += v * w.w;
  }
  acc.x = fmaxf(acc.x, 0.f); acc.y = fmaxf(acc.y, 0.f);
  acc.z = fmaxf(acc.z, 0.f); acc.w = fmaxf(acc.w, 0.f);
  *(float4*)&h[(size_t)g * H_N + lane * 4] = acc;
  if (is_var) {
    ushort4 q;
    q.x = f2bf(acc.x); q.y = f2bf(acc.y); q.z = f2bf(acc.z); q.w = f2bf(acc.w);
    *(ushort4*)&h_var_bf[(size_t)g * H_N + lane * 4] = q;
  }
}

// ---------------- batched bf16 row gather (8B/lane, 16 deep, 32-VGPR buffer) ---

static __device__ __forceinline__ void gather_rows_bf16(const u16* __restrict__ tbl,
                                                        const int* __restrict__ src,
                                                        int s, int e, int lane,
                                                        float4& acc) {
  int p = s;
  for (; p + 16 <= e; p += 16) {
    int myidx = src[p + lane];
    ushort4 vv[16];
#pragma unroll
    for (int j = 0; j < 16; ++j) {
      int sj = __shfl(myidx, j, 16);
      vv[j] = *(const ushort4*)&tbl[(size_t)sj * H_N + lane * 4];
    }
#pragma unroll
    for (int j = 0; j < 16; ++j) {
      acc.x += bf2f(vv[j].x); acc.y += bf2f(vv[j].y);
      acc.z += bf2f(vv[j].z); acc.w += bf2f(vv[j].w);
    }
  }
  if (p < e) {
    int cnt = e - p;
    int myidx = (lane < cnt) ? src[p + lane] : 0;
    ushort4 vv[16];
#pragma unroll
    for (int j = 0; j < 16; ++j) {
      int sj = __shfl(myidx, j, 16);
      vv[j] = *(const ushort4*)&tbl[(size_t)sj * H_N + lane * 4];
    }
#pragma unroll
    for (int j = 0; j < 16; ++j) {
      if (j < cnt) {
        acc.x += bf2f(vv[j].x); acc.y += bf2f(vv[j].y);
        acc.z += bf2f(vv[j].z); acc.w += bf2f(vv[j].w);
      }
    }
  }
}

// ---------------- fused C-side update (8 waves/block, 1 tile/wave, static) -----

__global__ __launch_bounds__(512) void fused_c(const u16* __restrict__ h_var_bf,
                                               const int* __restrict__ rs,
                                               const int* __restrict__ src,
                                               const u16* __restrict__ wp,
                                               const float* __restrict__ b1g,
                                               float* __restrict__ h_con,
                                               u16* __restrict__ t_out) {
  __shared__ u16 Wlds[4 * 64 * 64];              // 32768 B: [mat*2+pl][col][k]
  __shared__ u16 Aplane[FC_WAVES][16 * KPAD];    // 8 waves x 2304 B, hi/lo reused

  for (int i = threadIdx.x; i < 4 * 64 * 64 / 2; i += 512)
    ((u32*)Wlds)[i] = ((const u32*)wp)[i];
  __syncthreads();

  int lane64 = threadIdx.x & 63;
  int wave = threadIdx.x >> 6;
  int lane = threadIdx.x & 15;
  int grp = (threadIdx.x >> 4) & 3;
  int arow = lane64 & 15;     // A row / D col (within tile)
  int kq = lane64 >> 4;       // k-octet selector / D row-quad
  u16* P = &Aplane[wave][0];

  int tile = blockIdx.x * FC_WAVES + wave;
  if (tile >= NTILES_C) return;
  int base = tile * 16;

  float bias[4];
#pragma unroll
  for (int nt = 0; nt < 4; ++nt) bias[nt] = b1g[nt * 16 + arow];

  // ---- gather all 4 of this group's rows; keep sums in registers
  float4 accs[4];
#pragma unroll
  for (int q = 0; q < 4; ++q) {
    int row = 4 * q + grp;
    int g = base + row;
    float4 a = {0.f, 0.f, 0.f, 0.f};
    if (g < C_N) gather_rows_bf16(h_var_bf, src, rs[g], rs[g + 1], lane, a);
    accs[q] = a;
  }
  // ---- pass 1: stage hi plane, read A1h
#pragma unroll
  for (int q = 0; q < 4; ++q) {
    int row = 4 * q + grp;
    ushort4 qh;
    qh.x = f2bf(accs[q].x); qh.y = f2bf(accs[q].y);
    qh.z = f2bf(accs[q].z); qh.w = f2bf(accs[q].w);
    *(ushort4*)&P[row * KPAD + lane * 4] = qh;
  }
  asm volatile("" ::: "memory");
  short8v A1h[2];
#pragma unroll
  for (int ks = 0; ks < 2; ++ks)
    A1h[ks] = *(const short8v*)&P[arow * KPAD + ks * 32 + kq * 8];
  asm volatile("" ::: "memory");
  // ---- pass 2: stage lo plane (overwrite), read A1l
#pragma unroll
  for (int q = 0; q < 4; ++q) {
    int row = 4 * q + grp;
    ushort4 ql;
    ql.x = f2bf(accs[q].x - bf2f(f2bf(accs[q].x)));
    ql.y = f2bf(accs[q].y - bf2f(f2bf(accs[q].y)));
    ql.z = f2bf(accs[q].z - bf2f(f2bf(accs[q].z)));
    ql.w = f2bf(accs[q].w - bf2f(f2bf(accs[q].w)));
    *(ushort4*)&P[row * KPAD + lane * 4] = ql;
  }
  asm volatile("" ::: "memory");
  short8v A1l[2];
#pragma unroll
  for (int ks = 0; ks < 2; ++ks)
    A1l[ks] = *(const short8v*)&P[arow * KPAD + ks * 32 + kq * 8];
  asm volatile("" ::: "memory");
  // ---- matvec1 + residual + relu; keep hn in regs
  float hn[4][4];  // [nt][r]
#pragma unroll
  for (int nt = 0; nt < 4; ++nt) {
    int bcol = nt * 16 + arow;
    f32x4 c = {0.f, 0.f, 0.f, 0.f};
#pragma unroll
    for (int ks = 0; ks < 2; ++ks) {
      short8v Bh = *(const short8v*)&Wlds[(0 * 64 + bcol) * 64 + ks * 32 + kq * 8];
      short8v Bl = *(const short8v*)&Wlds[(1 * 64 + bcol) * 64 + ks * 32 + kq * 8];
      c = __builtin_amdgcn_mfma_f32_16x16x32_bf16(A1h[ks], Bh, c, 0, 0, 0);
      c = __builtin_amdgcn_mfma_f32_16x16x32_bf16(A1l[ks], Bh, c, 0, 0, 0);
      c = __builtin_amdgcn_mfma_f32_16x16x32_bf16(A1h[ks], Bl, c, 0, 0, 0);
    }
#pragma unroll
    for (int r = 0; r < 4; ++r) {
      int row = kq * 4 + r;
      int g = base + row;
      float hv = (g < C_N) ? h_con[(size_t)g * H_N + nt * 16 + arow] : 0.f;
      float v = fmaxf(hv + c[r] + bias[nt], 0.f);
      if (g < C_N) h_con[(size_t)g * H_N + nt * 16 + arow] = v;
      hn[nt][r] = v;
    }
  }
  // ---- pass 1: stage hn hi plane, read A2h
#pragma unroll
  for (int nt = 0; nt < 4; ++nt)
#pragma unroll
    for (int r = 0; r < 4; ++r)
      P[(kq * 4 + r) * KPAD + nt * 16 + arow] = f2bf(hn[nt][r]);
  asm volatile("" ::: "memory");
  short8v A2h[2];
#pragma unroll
  for (int ks = 0; ks < 2; ++ks)
    A2h[ks] = *(const short8v*)&P[arow * KPAD + ks * 32 + kq * 8];
  asm volatile("" ::: "memory");
  // ---- pass 2: stage hn lo plane, read A2l
#pragma unroll
  for (int nt = 0; nt < 4; ++nt)
#pragma unroll
    for (int r = 0; r < 4; ++r) {
      u16 hi = f2bf(hn[nt][r]);
      P[(kq * 4 + r) * KPAD + nt * 16 + arow] = f2bf(hn[nt][r] - bf2f(hi));
    }
  asm volatile("" ::: "memory");
  short8v A2l[2];
#pragma unroll
  for (int ks = 0; ks < 2; ++ks)
    A2l[ks] = *(const short8v*)&P[arow * KPAD + ks * 32 + kq * 8];
  asm volatile("" ::: "memory");
  // ---- matvec2 -> t_bf
#pragma unroll
  for (int nt = 0; nt < 4; ++nt) {
    int bcol = nt * 16 + arow;
    f32x4 c = {0.f, 0.f, 0.f, 0.f};
#pragma unroll
    for (int ks = 0; ks < 2; ++ks) {
      short8v Bh = *(const short8v*)&Wlds[(2 * 64 + bcol) * 64 + ks * 32 + kq * 8];
      short8v Bl = *(const short8v*)&Wlds[(3 * 64 + bcol) * 64 + ks * 32 + kq * 8];
      c = __builtin_amdgcn_mfma_f32_16x16x32_bf16(A2h[ks], Bh, c, 0, 0, 0);
      c = __builtin_amdgcn_mfma_f32_16x16x32_bf16(A2l[ks], Bh, c, 0, 0, 0);
      c = __builtin_amdgcn_mfma_f32_16x16x32_bf16(A2h[ks], Bl, c, 0, 0, 0);
    }
#pragma unroll
    for (int r = 0; r < 4; ++r) {
      int row = kq * 4 + r;
      int g = base + row;
      if (g < C_N) t_out[(size_t)g * H_N + nt * 16 + arow] = f2bf(c[r]);
    }
  }
}

// ---------------- V-side gather (+ fused score epilogue on last round) ----------

template <int DO_SCORE>
__global__ __launch_bounds__(256) void gather_v_k(const u16* __restrict__ t,
                                                  const int* __restrict__ rs,
                                                  const int* __restrict__ src,
                                                  const float* __restrict__ bias,
                                                  float* __restrict__ h,
                                                  u16* __restrict__ hbf,
                                                  const float* __restrict__ Ws,
                                                  const float* __restrict__ bs,
                                                  float* __restrict__ out) {
  int g = (blockIdx.x * 256 + threadIdx.x) >> 4;
  int lane = threadIdx.x & 15;
  if (g >= V_N) return;
  int s = rs[g], e = rs[g + 1];
  float4 acc = {0.f, 0.f, 0.f, 0.f};
  gather_rows_bf16(t, src, s, e, lane, acc);
  float4 hv = *(const float4*)&h[(size_t)g * H_N + lane * 4];
  float4 b4 = *(const float4*)&bias[lane * 4];
  float4 hn;
  hn.x = fmaxf(hv.x + acc.x + b4.x, 0.f);
  hn.y = fmaxf(hv.y + acc.y + b4.y, 0.f);
  hn.z = fmaxf(hv.z + acc.z + b4.z, 0.f);
  hn.w = fmaxf(hv.w + acc.w + b4.w, 0.f);
  if (DO_SCORE) {
    float4 w = *(const float4*)&Ws[lane * 4];
    float d = hn.x * w.x + hn.y * w.y + hn.z * w.z + hn.w * w.w;
    d += __shfl_down(d, 8, 16);
    d += __shfl_down(d, 4, 16);
    d += __shfl_down(d, 2, 16);
    d += __shfl_down(d, 1, 16);
    if (lane == 0) out[g] = d + bs[0];
  } else {
    *(float4*)&h[(size_t)g * H_N + lane * 4] = hn;
    ushort4 q;
    q.x = f2bf(hn.x); q.y = f2bf(hn.y); q.z = f2bf(hn.z); q.w = f2bf(hn.w);
    *(ushort4*)&hbf[(size_t)g * H_N + lane * 4] = q;
  }
}

// ---------------- launch ----------------

extern "C" void kernel_launch(void* const* d_in, const int* in_sizes, int n_in,
                              void* d_out, int out_size, void* d_ws, size_t ws_size,
                              hipStream_t stream) {
  const float* var_feat = (const float*)d_in[0];
  const float* con_feat = (const float*)d_in[1];
  const float* W_var = (const float*)d_in[2];
  const float* b_var = (const float*)d_in[3];
  const float* W_con = (const float*)d_in[4];
  const float* b_con = (const float*)d_in[5];
  const float* W_v2c = (const float*)d_in[6];
  const float* b_v2c = (const float*)d_in[7];
  const float* W_c2v = (const float*)d_in[8];
  const float* b_c2v = (const float*)d_in[9];
  const float* W_score = (const float*)d_in[10];
  const float* b_score = (const float*)d_in[11];
  const int* var_idx = (const int*)d_in[12];
  const int* constr_idx = (const int*)d_in[13];
  float* out = (float*)d_out;

  char* p = (char*)d_ws;
  auto alloc = [&](size_t bytes) {
    char* r = p;
    p += (bytes + 255) & ~(size_t)255;
    return r;
  };
  float* h_var = (float*)alloc((size_t)V_N * H_N * 4);
  u16* h_var_bf = (u16*)alloc((size_t)V_N * H_N * 2);
  float* h_con = (float*)alloc((size_t)C_N * H_N * 4);
  u16* t_bf = (u16*)alloc((size_t)C_N * H_N * 2);
  u16* wp = (u16*)alloc((size_t)4 * 64 * 64 * 2);
  int* rs_c = (int*)alloc((size_t)(C_N + 1) * 4);
  int* rs_v = (int*)alloc((size_t)(V_N + 1) * 4);
  int* src_c = (int*)alloc((size_t)E_N * 4);
  int* src_v = (int*)alloc((size_t)E_N * 4);
  int* packed_c = (int*)alloc((size_t)E_N * 4);
  int* packed_v = (int*)alloc((size_t)E_N * 4);
  int* ghist_c = (int*)alloc((size_t)NB_C * 4);
  int* ghist_v = (int*)alloc((size_t)NB_V * 4);
  int* base_c = (int*)alloc((size_t)(NB_C + 1) * 4);
  int* base_v = (int*)alloc((size_t)(NB_V + 1) * 4);
  int* cursor_c = (int*)alloc((size_t)NB_C * 4);
  int* cursor_v = (int*)alloc((size_t)NB_V * 4);

  hipMemsetAsync(ghist_c, 0, (size_t)NB_C * 4, stream);
  hipMemsetAsync(ghist_v, 0, (size_t)NB_V * 4, stream);

  bucket_hist<<<NT, 256, 0, stream>>>(var_idx, constr_idx, ghist_c, ghist_v);
  bucket_scan<<<1, 512, 0, stream>>>(ghist_c, ghist_v, base_c, cursor_c,
                                     base_v, cursor_v, rs_c, rs_v);
  scatter_pack<<<NT, 256, 0, stream>>>(var_idx, constr_idx, cursor_c, cursor_v,
                                       packed_c, packed_v);
  fine_sort_both<<<NB_C + NB_V, 256, 0, stream>>>(packed_c, base_c, rs_c, src_c,
                                                  packed_v, base_v, rs_v, src_v);

  init_all<<<MLP_NB_V + MLP_NB_C + 16, 256, 0, stream>>>(
      var_feat, W_var, b_var, h_var, h_var_bf,
      con_feat, W_con, b_con, h_con,
      W_v2c, W_c2v, wp);

  for (int r = 0; r < ROUNDS; ++r) {
    fused_c<<<FC_BLOCKS, 512, 0, stream>>>(h_var_bf, rs_c, src_c, wp,
                                           b_v2c, h_con, t_bf);
    if (r < ROUNDS - 1) {
      gather_v_k<0><<<(V_N + 15) / 16, 256, 0, stream>>>(t_bf, rs_v, src_v, b_c2v, h_var,
                                                         h_var_bf, nullptr, nullptr, nullptr);
    } else {
      gather_v_k<1><<<(V_N + 15) / 16, 256, 0, stream>>>(t_bf, rs_v, src_v, b_c2v, h_var,
                                                         nullptr, W_score, b_score, out);
    }
  }
}